// Round 17
// baseline (1293.021 us; speedup 1.0000x reference)
//
#include <hip/hip_runtime.h>
#include <math.h>

#define B 4
#define C 200
#define H 128
#define W 128
#define N 16384   // H*W
#define K 256
#define ITERS 5
#define FACT 1.25f   // COMPACTNESS / S = 10 / 8
#define NT 32        // split-K n-tiles for the update GEMM (512 n each)
#define NCT 10       // c-tiles for the update GEMM (20 c each)
#define NTM 128      // n-tiles for k_mass (128 n each)

// workspace layout (floats)
#define OFF_A2    0
#define OFF_CS    (OFF_A2 + B*N)            // 65536
#define OFF_CSPAT (OFF_CS + B*K*C)          // 270336
#define OFF_B2    (OFF_CSPAT + B*K*2)       // 272384
#define OFF_SACC  (OFF_B2 + B*K)            // 273408
#define OFF_MACC  (OFF_SACC + B*K*C)        // 478208
#define OFF_SPACC (OFF_MACC + B*K)          // 479232
#define OFF_CST   (OFF_SPACC + B*K*2)       // 481280  transposed centers [B][C][K]
#define CST_SZ    (B*C*K)                   // 204800
#define OFF_PART  (OFF_CST + CST_SZ)        // 686080
#define PART_SZ   (B*NT*NCT*20*K)           // 6,553,600 floats (26.2 MB)
#define OFF_MPART (OFF_PART + PART_SZ)
#define MPART_SZ  (B*NTM*3*K)               // 393,216 floats
#define WS_NEED   ((size_t)(OFF_MPART + MPART_SZ) * 4)

// ---------------------------------------------------------------------------
// init: centers_spectral[b,k,c] = x[0,c,seed_n(k)]; also transposed cs_t
__global__ void k_init(const float* __restrict__ x, float* __restrict__ cs,
                       float* __restrict__ cst, float* __restrict__ cspat) {
  int k = blockIdx.x, c = threadIdx.x;
  int i = k >> 4, j = k & 15;
  int sn = (4 + 8*i)*W + (4 + 8*j);
  if (c < C) {
    float v = x[(size_t)c*N + sn];
    for (int b = 0; b < B; ++b) {
      cs[((size_t)(b*K + k))*C + c] = v;
      cst[((size_t)(b*C + c))*K + k] = v;
    }
  }
  if (c == 0) {
    for (int b = 0; b < B; ++b) {
      cspat[(b*K + k)*2 + 0] = (float)(4 + 8*i);
      cspat[(b*K + k)*2 + 1] = (float)(4 + 8*j);
    }
  }
}

// a2[b,n] = sum_c x[b,c,n]^2  (iteration-invariant)
__global__ void k_a2(const float* __restrict__ x, float* __restrict__ a2) {
  int b = blockIdx.x >> 6;
  int n = ((blockIdx.x & 63) << 8) + threadIdx.x;
  const float* xp = x + (size_t)b*C*N + n;
  float s = 0.f;
  #pragma unroll 8
  for (int c = 0; c < C; ++c) { float v = xp[(size_t)c*N]; s += v*v; }
  a2[b*N + n] = s;
}

// b2[b,k] = sum_c cs[b,k,c]^2
__global__ void k_b2(const float* __restrict__ cs, float* __restrict__ b2) {
  int bk = blockIdx.x;
  const float* p = cs + (size_t)bk*C;
  float s = 0.f;
  for (int c = threadIdx.x; c < C; c += 64) { float v = p[c]; s += v*v; }
  for (int off = 32; off > 0; off >>= 1) s += __shfl_down(s, off);
  if (threadIdx.x == 0) b2[bk] = s;
}

// ---------------------------------------------------------------------------
// assignment v10 (unchanged from R16): register-tiled GEMM, 8k x 8px/thread.
__global__ __launch_bounds__(512, 2) void k_assign(
    const float* __restrict__ x, const float* __restrict__ cst,
    const float* __restrict__ cspat, const float* __restrict__ b2,
    const float* __restrict__ a2, float* __restrict__ Q) {
  __shared__ float cs_lds[40*K];    // 40960 B [c][k]
  __shared__ float xr_lds[40*128];  // 20480 B [c][p]; reused as redp/redf
  __shared__ float b2s[K], cys[K], cxs[K];  // 3072 B
  float* redp = xr_lds;             // [32][136] = 4352 floats
  float* redf = xr_lds + 4352;      // [128]

  int b   = blockIdx.x >> 7;          // 128 blocks per batch
  int n0  = (blockIdx.x & 127) << 7;  // 128 pixels per block
  int tid = threadIdx.x;
  int kgi = tid >> 4;                 // 0..31
  int k0  = kgi << 3;                 // 8 k per thread
  int p0  = (tid & 15) << 3;          // 8 px per thread

  if (tid < K) {
    b2s[tid] = b2[b*K + tid];
    cys[tid] = cspat[(b*K + tid)*2 + 0];
    cxs[tid] = cspat[(b*K + tid)*2 + 1];
  }

  float acc[64];   // [kk][pp] = acc[kk*8+pp]
  #pragma unroll
  for (int i = 0; i < 64; ++i) acc[i] = 0.f;

  const float* xb = x + (size_t)b*C*N;
  const float* ct = cst + (size_t)b*C*K;
  float4* cs4 = (float4*)cs_lds;
  float4* xr4 = (float4*)xr_lds;

  for (int t = 0; t < 5; ++t) {
    int cc0 = t * 40;
    __syncthreads();
    #pragma unroll
    for (int pass = 0; pass < 5; ++pass) {   // cs_t tile: linear copy 2560 f4
      int f = pass*512 + tid;
      cs4[f] = *(const float4*)&ct[(size_t)cc0*K + f*4];
    }
    #pragma unroll
    for (int pass = 0; pass < 3; ++pass) {   // x tile [40c][128p]: 1280 f4
      int idx = pass*512 + tid;
      if (idx < 1280) {
        int ci = idx >> 5, pq = idx & 31;
        xr4[idx] = *(const float4*)&xb[(size_t)(cc0 + ci)*N + n0 + pq*4];
      }
    }
    __syncthreads();
    #pragma unroll 2
    for (int c = 0; c < 40; ++c) {
      float4 cv0 = *(const float4*)&cs_lds[c*256 + k0];
      float4 cv1 = *(const float4*)&cs_lds[c*256 + k0 + 4];
      float4 xv0 = *(const float4*)&xr_lds[c*128 + p0];
      float4 xv1 = *(const float4*)&xr_lds[c*128 + p0 + 4];
      float cr[8] = {cv0.x, cv0.y, cv0.z, cv0.w, cv1.x, cv1.y, cv1.z, cv1.w};
      float xr[8] = {xv0.x, xv0.y, xv0.z, xv0.w, xv1.x, xv1.y, xv1.z, xv1.w};
      #pragma unroll
      for (int kk = 0; kk < 8; ++kk)
        #pragma unroll
        for (int pp = 0; pp < 8; ++pp)
          acc[kk*8 + pp] = fmaf(cr[kk], xr[pp], acc[kk*8 + pp]);
    }
  }
  __syncthreads();   // all x_lds reads done before redp overlay writes

  // ---- distances ----
  float py  = (float)(n0 >> 7);          // all 128 px share one image row
  float pxb = (float)(n0 & 127);
  float a2v[8], mn[8];
  #pragma unroll
  for (int pp = 0; pp < 8; ++pp) {
    a2v[pp] = a2[b*N + n0 + p0 + pp];
    mn[pp] = 1e30f;
  }
  #pragma unroll
  for (int kk = 0; kk < 8; ++kk) {
    int k = k0 + kk;
    float b2v = b2s[k], cy = cys[k], cx = cxs[k];
    float dy = py - cy, dyy = dy*dy;
    #pragma unroll
    for (int pp = 0; pp < 8; ++pp) {
      float dx = pxb + (float)(p0 + pp) - cx;
      float d = sqrtf(fmaxf(a2v[pp] + b2v - 2.f*acc[kk*8+pp], 1e-12f))
              + FACT*sqrtf(fmaxf(dyy + dx*dx, 1e-12f));
      acc[kk*8+pp] = d;
      mn[pp] = fminf(mn[pp], d);
    }
  }
  // ---- softmax over K: two-stage reduce across 32 kgroups ----
  #pragma unroll
  for (int pp = 0; pp < 8; ++pp) redp[kgi*136 + p0 + pp] = mn[pp];
  __syncthreads();
  if (tid < 128) {
    float m = redp[tid];
    #pragma unroll
    for (int g = 1; g < 32; ++g) m = fminf(m, redp[g*136 + tid]);
    redf[tid] = m;
  }
  __syncthreads();
  #pragma unroll
  for (int pp = 0; pp < 8; ++pp) mn[pp] = redf[p0 + pp];
  float sm[8] = {0.f,0.f,0.f,0.f,0.f,0.f,0.f,0.f};
  #pragma unroll
  for (int kk = 0; kk < 8; ++kk)
    #pragma unroll
    for (int pp = 0; pp < 8; ++pp) {
      float e = __expf(mn[pp] - acc[kk*8+pp]);
      acc[kk*8+pp] = e;
      sm[pp] += e;
    }
  __syncthreads();   // redf min-reads done before sum overwrite path
  #pragma unroll
  for (int pp = 0; pp < 8; ++pp) redp[kgi*136 + p0 + pp] = sm[pp];
  __syncthreads();
  if (tid < 128) {
    float s = redp[tid];
    #pragma unroll
    for (int g = 1; g < 32; ++g) s += redp[g*136 + tid];
    redf[tid] = 1.f / s;
  }
  __syncthreads();
  #pragma unroll
  for (int pp = 0; pp < 8; ++pp) {
    float inv = redf[p0 + pp];
    float* qp = Q + ((size_t)(b*N + n0 + p0 + pp))*K + k0;
    float4 v0 = make_float4(acc[0*8+pp]*inv, acc[1*8+pp]*inv,
                            acc[2*8+pp]*inv, acc[3*8+pp]*inv);
    float4 v1 = make_float4(acc[4*8+pp]*inv, acc[5*8+pp]*inv,
                            acc[6*8+pp]*inv, acc[7*8+pp]*inv);
    *(float4*)&qp[0] = v0;
    *(float4*)&qp[4] = v1;
  }
}

// ---------------------------------------------------------------------------
// update v6 stage 1: register-tiled 4k x 5c, finer c-split for occupancy.
// grid = B*NCT*NT = 1280 (5 blocks/CU, 4 resident at 35KB LDS -> 16 waves/CU).
// 256 thr = 64 kgroups(4k) x 4 cgroups(5c). Block = 256k x 20c x 512n.
__global__ __launch_bounds__(256) void k_update3(
    const float* __restrict__ x, const float* __restrict__ Q,
    float* __restrict__ part) {
  __shared__ float q_lds[32*256];   // 32 KB [n][k]
  __shared__ float x_lds[20*34];    // 2.7 KB [c][n] pad 34
  int bid = blockIdx.x;             // B*NCT*NT = 1280
  int b   = bid / (NCT*NT);
  int rem = bid - b*(NCT*NT);
  int ct  = rem >> 5;               // 0..9
  int nt  = rem & 31;               // 0..31
  int tid = threadIdx.x;
  int kg  = tid & 63;               // 64 kgroups
  int k0  = kg << 2;                // 4 k per thread
  int cg  = tid >> 6;               // 4 cgroups (wave-uniform)
  int cbase = cg * 5;               // 5 c per thread
  int c0  = ct * 20;

  float acc[20];                    // [kk][c] = acc[kk*5 + c]
  #pragma unroll
  for (int i = 0; i < 20; ++i) acc[i] = 0.f;

  const float* xb = x + (size_t)b*C*N + (size_t)c0*N;
  const float4* Q4 = (const float4*)(Q + (size_t)b*N*K);
  float4* q4 = (float4*)q_lds;

  for (int ch = 0; ch < 16; ++ch) {
    int nb = nt*512 + ch*32;
    __syncthreads();
    #pragma unroll
    for (int pass = 0; pass < 8; ++pass) {   // Q tile: 2048 f4, linear
      int idx = pass*256 + tid;
      q4[idx] = Q4[(size_t)(nb + (idx >> 6))*64 + (idx & 63)];
    }
    {                                        // x tile [20c][34n]: 640 elems
      int idx = tid;
      #pragma unroll
      for (int pass = 0; pass < 3; ++pass) {
        if (idx < 640) {
          int ci = idx >> 5, nn = idx & 31;
          x_lds[ci*34 + nn] = xb[(size_t)ci*N + nb + nn];
        }
        idx += 256;
      }
    }
    __syncthreads();
    #pragma unroll 4
    for (int nn = 0; nn < 32; nn += 2) {
      float4 qv0 = *(const float4*)&q_lds[nn*256 + k0];
      float4 qv1 = *(const float4*)&q_lds[(nn+1)*256 + k0];
      float qr0[4] = {qv0.x, qv0.y, qv0.z, qv0.w};
      float qr1[4] = {qv1.x, qv1.y, qv1.z, qv1.w};
      #pragma unroll
      for (int c = 0; c < 5; ++c) {
        float2 xv = *(const float2*)&x_lds[(cbase + c)*34 + nn]; // broadcast
        #pragma unroll
        for (int kk = 0; kk < 4; ++kk) {
          float a = acc[kk*5 + c];
          a = fmaf(qr0[kk], xv.x, a);
          a = fmaf(qr1[kk], xv.y, a);
          acc[kk*5 + c] = a;
        }
      }
    }
  }
  // coalesced f4 partial stores (consecutive kg -> consecutive 16B)
  float* pp = part + ((size_t)((b*NT + nt)*NCT + ct) * 20) * K;
  #pragma unroll
  for (int c = 0; c < 5; ++c) {
    float4 v = make_float4(acc[0*5+c], acc[1*5+c], acc[2*5+c], acc[3*5+c]);
    *(float4*)&pp[(size_t)(cbase + c)*K + k0] = v;
  }
}

// mass/spatial sums: mass[k] = sum_n Q[n][k], etc. grid = B*NTM, 128 n each.
__global__ __launch_bounds__(256) void k_mass(
    const float* __restrict__ Q, float* __restrict__ mpart) {
  int bid = blockIdx.x;             // B*NTM = 512
  int b = bid >> 7, nt = bid & 127;
  int tid = threadIdx.x;
  const float* Qb = Q + (size_t)b*N*K;
  int nbase = nt * 128;
  float mass = 0.f, sy = 0.f, sx = 0.f;
  for (int nn = 0; nn < 128; nn += 8) {
    float qv[8];
    #pragma unroll
    for (int j = 0; j < 8; ++j)
      qv[j] = Qb[(size_t)(nbase + nn + j)*K + tid];
    #pragma unroll
    for (int j = 0; j < 8; ++j) {
      int n = nbase + nn + j;
      mass += qv[j];
      sy += qv[j] * (float)(n >> 7);
      sx += qv[j] * (float)(n & 127);
    }
  }
  float* mp = mpart + (size_t)(b*NTM + nt) * 3 * K;
  mp[tid]       = mass;
  mp[K + tid]   = sy;
  mp[2*K + tid] = sx;
}

// stage 2: reduce NT partials per output element. grid = B*200.
__global__ __launch_bounds__(256) void k_reduce(
    const float* __restrict__ part, const float* __restrict__ mpart,
    float* __restrict__ sacc, float* __restrict__ macc,
    float* __restrict__ spacc) {
  int bid = blockIdx.x;        // B * 200
  int b = bid / 200;
  int r = bid % 200;
  int ct = r / 20, cw = r % 20;
  int tid = threadIdx.x;
  float s = 0.f;
  for (int nt = 0; nt < NT; ++nt)
    s += part[(((size_t)(b*NT + nt)*NCT + ct)*20 + cw)*K + tid];
  sacc[(size_t)(b*K + tid)*C + ct*20 + cw] = s;
  if (r == 0) {
    float m = 0.f, yy = 0.f, xx = 0.f;
    for (int nt = 0; nt < NTM; ++nt) {
      const float* mp = mpart + (size_t)(b*NTM + nt) * 3 * K;
      m  += mp[tid];
      yy += mp[K + tid];
      xx += mp[2*K + tid];
    }
    macc[b*K + tid] = m;
    spacc[(b*K + tid)*2 + 0] = yy;
    spacc[(b*K + tid)*2 + 1] = xx;
  }
}

// ---------------------------------------------------------------------------
// fallback update (atomic version, used only if ws too small for partials)
__global__ __launch_bounds__(256, 2) void k_update(
    const float* __restrict__ x, const float* __restrict__ Q,
    float* __restrict__ sacc, float* __restrict__ macc,
    float* __restrict__ spacc) {
  __shared__ float x_lds[32*28];
  int bid = blockIdx.x;
  int b = bid >> 9;
  int rest = bid & 511;
  int ct = rest >> 6;
  int nt = rest & 63;
  int tid = threadIdx.x;
  int c0 = ct * 25;

  float acc[25];
  #pragma unroll
  for (int c = 0; c < 25; ++c) acc[c] = 0.f;
  float mass = 0.f, sy = 0.f, sx = 0.f;

  const float* xb = x + (size_t)b*C*N + (size_t)c0*N;
  const float* Qb = Q + (size_t)b*N*K;

  for (int ch = 0; ch < 8; ++ch) {
    int nb = nt*256 + ch*32;
    __syncthreads();
    #pragma unroll
    for (int pass = 0; pass < 4; ++pass) {
      int idx = pass*256 + tid;
      if (idx < 800) {
        int ci = idx >> 5, nn = idx & 31;
        x_lds[nn*28 + ci] = xb[(size_t)ci*N + nb + nn];
      }
    }
    __syncthreads();
    float py  = (float)(nb >> 7);
    float pxb = (float)(nb & 127);
    #pragma unroll
    for (int n4 = 0; n4 < 8; ++n4) {
      float qv[4];
      #pragma unroll
      for (int j = 0; j < 4; ++j)
        qv[j] = Qb[(size_t)(nb + n4*4 + j)*K + tid];
      #pragma unroll
      for (int j = 0; j < 4; ++j) {
        int nn = n4*4 + j;
        float q = qv[j];
        if (ct == 0) {
          mass += q;
          sy += q * py;
          sx += q * (pxb + (float)nn);
        }
        const float* xr = &x_lds[nn*28];
        #pragma unroll
        for (int c4 = 0; c4 < 6; ++c4) {
          float4 xv = *(const float4*)&xr[c4*4];
          acc[c4*4+0] = fmaf(q, xv.x, acc[c4*4+0]);
          acc[c4*4+1] = fmaf(q, xv.y, acc[c4*4+1]);
          acc[c4*4+2] = fmaf(q, xv.z, acc[c4*4+2]);
          acc[c4*4+3] = fmaf(q, xv.w, acc[c4*4+3]);
        }
        acc[24] = fmaf(q, xr[24], acc[24]);
      }
    }
  }
  float* sp = sacc + ((size_t)(b*K + tid))*C + c0;
  #pragma unroll
  for (int c = 0; c < 25; ++c) atomicAdd(&sp[c], acc[c]);
  if (ct == 0) {
    atomicAdd(&macc[b*K + tid], mass);
    atomicAdd(&spacc[(b*K + tid)*2 + 0], sy);
    atomicAdd(&spacc[(b*K + tid)*2 + 1], sx);
  }
}

// finalize: divide by mass; write centers (row-major + transposed) and d_out
__global__ void k_final(const float* __restrict__ sacc, const float* __restrict__ macc,
                        const float* __restrict__ spacc, float* __restrict__ cs,
                        float* __restrict__ cst, float* __restrict__ cspat,
                        float* __restrict__ outc, int last) {
  int bk = blockIdx.x;
  int b = bk >> 8, kk = bk & 255;
  int c = threadIdx.x;
  float inv = 1.f / (macc[bk] + 1e-6f);
  if (c < C) {
    float v = sacc[(size_t)bk*C + c] * inv;
    cs[(size_t)bk*C + c] = v;
    cst[((size_t)(b*C + c))*K + kk] = v;
    if (last) outc[(size_t)bk*C + c] = v;
  } else if (c == C) {
    cspat[bk*2 + 0] = spacc[bk*2 + 0] * inv;
  } else if (c == C + 1) {
    cspat[bk*2 + 1] = spacc[bk*2 + 1] * inv;
  }
}

extern "C" void kernel_launch(void* const* d_in, const int* in_sizes, int n_in,
                              void* d_out, int out_size, void* d_ws, size_t ws_size,
                              hipStream_t stream) {
  const float* x = (const float*)d_in[0];
  float* out = (float*)d_out;
  float* ws  = (float*)d_ws;
  float* a2    = ws + OFF_A2;
  float* cs    = ws + OFF_CS;
  float* cspat = ws + OFF_CSPAT;
  float* b2    = ws + OFF_B2;
  float* sacc  = ws + OFF_SACC;
  float* macc  = ws + OFF_MACC;
  float* spacc = ws + OFF_SPACC;
  float* cst   = ws + OFF_CST;
  float* part  = ws + OFF_PART;
  float* mpart = ws + OFF_MPART;
  float* outc  = out + (size_t)B*N*K;
  int split = (ws_size >= WS_NEED) ? 1 : 0;

  hipLaunchKernelGGL(k_init, dim3(K), dim3(256), 0, stream, x, cs, cst, cspat);
  hipLaunchKernelGGL(k_a2, dim3(B*64), dim3(256), 0, stream, x, a2);
  for (int it = 0; it < ITERS; ++it) {
    hipLaunchKernelGGL(k_b2, dim3(B*K), dim3(64), 0, stream, cs, b2);
    hipLaunchKernelGGL(k_assign, dim3(B*128), dim3(512), 0, stream,
                       x, cst, cspat, b2, a2, out);
    if (split) {
      hipLaunchKernelGGL(k_update3, dim3(B*NCT*NT), dim3(256), 0, stream,
                         x, out, part);
      hipLaunchKernelGGL(k_mass, dim3(B*NTM), dim3(256), 0, stream,
                         out, mpart);
      hipLaunchKernelGGL(k_reduce, dim3(B*200), dim3(256), 0, stream,
                         part, mpart, sacc, macc, spacc);
    } else {
      hipMemsetAsync(sacc, 0, (size_t)(B*K*C + B*K + B*K*2)*sizeof(float), stream);
      hipLaunchKernelGGL(k_update, dim3(B*512), dim3(256), 0, stream,
                         x, out, sacc, macc, spacc);
    }
    hipLaunchKernelGGL(k_final, dim3(B*K), dim3(256), 0, stream,
                       sacc, macc, spacc, cs, cst, cspat, outc,
                       (it == ITERS-1) ? 1 : 0);
  }
}

// Round 18
// 1254.051 us; speedup vs baseline: 1.0311x; 1.0311x over previous
//
#include <hip/hip_runtime.h>
#include <math.h>

#define B 4
#define C 200
#define H 128
#define W 128
#define N 16384   // H*W
#define K 256
#define ITERS 5
#define FACT 1.25f   // COMPACTNESS / S = 10 / 8
#define NT 32        // split-K n-tiles for the update GEMM (512 n each)
#define NCT 5        // c-tiles for the update GEMM (40 c each)
#define NTM 128      // n-tiles for k_mass (128 n each)

// workspace layout (floats)
#define OFF_A2    0
#define OFF_CS    (OFF_A2 + B*N)            // 65536
#define OFF_CSPAT (OFF_CS + B*K*C)          // 270336
#define OFF_B2    (OFF_CSPAT + B*K*2)       // 272384
#define OFF_SACC  (OFF_B2 + B*K)            // 273408
#define OFF_MACC  (OFF_SACC + B*K*C)        // 478208
#define OFF_SPACC (OFF_MACC + B*K)          // 479232
#define OFF_CST   (OFF_SPACC + B*K*2)       // 481280  transposed centers [B][C][K]
#define CST_SZ    (B*C*K)                   // 204800
#define OFF_PART  (OFF_CST + CST_SZ)        // 686080
#define PART_SZ   (B*NT*NCT*40*K)           // 6,553,600 floats (26.2 MB)
#define OFF_MPART (OFF_PART + PART_SZ)
#define MPART_SZ  (B*NTM*3*K)               // 393,216 floats
#define WS_NEED   ((size_t)(OFF_MPART + MPART_SZ) * 4)

// ---------------------------------------------------------------------------
// init: centers_spectral[b,k,c] = x[0,c,seed_n(k)]; also transposed cs_t
__global__ void k_init(const float* __restrict__ x, float* __restrict__ cs,
                       float* __restrict__ cst, float* __restrict__ cspat) {
  int k = blockIdx.x, c = threadIdx.x;
  int i = k >> 4, j = k & 15;
  int sn = (4 + 8*i)*W + (4 + 8*j);
  if (c < C) {
    float v = x[(size_t)c*N + sn];
    for (int b = 0; b < B; ++b) {
      cs[((size_t)(b*K + k))*C + c] = v;
      cst[((size_t)(b*C + c))*K + k] = v;
    }
  }
  if (c == 0) {
    for (int b = 0; b < B; ++b) {
      cspat[(b*K + k)*2 + 0] = (float)(4 + 8*i);
      cspat[(b*K + k)*2 + 1] = (float)(4 + 8*j);
    }
  }
}

// a2[b,n] = sum_c x[b,c,n]^2  (iteration-invariant)
__global__ void k_a2(const float* __restrict__ x, float* __restrict__ a2) {
  int b = blockIdx.x >> 6;
  int n = ((blockIdx.x & 63) << 8) + threadIdx.x;
  const float* xp = x + (size_t)b*C*N + n;
  float s = 0.f;
  #pragma unroll 8
  for (int c = 0; c < C; ++c) { float v = xp[(size_t)c*N]; s += v*v; }
  a2[b*N + n] = s;
}

// b2[b,k] = sum_c cs[b,k,c]^2
__global__ void k_b2(const float* __restrict__ cs, float* __restrict__ b2) {
  int bk = blockIdx.x;
  const float* p = cs + (size_t)bk*C;
  float s = 0.f;
  for (int c = threadIdx.x; c < C; c += 64) { float v = p[c]; s += v*v; }
  for (int off = 32; off > 0; off >>= 1) s += __shfl_down(s, off);
  if (threadIdx.x == 0) b2[bk] = s;
}

// ---------------------------------------------------------------------------
// assignment v10 (unchanged from R16): register-tiled GEMM, 8k x 8px/thread.
__global__ __launch_bounds__(512, 2) void k_assign(
    const float* __restrict__ x, const float* __restrict__ cst,
    const float* __restrict__ cspat, const float* __restrict__ b2,
    const float* __restrict__ a2, float* __restrict__ Q) {
  __shared__ float cs_lds[40*K];    // 40960 B [c][k]
  __shared__ float xr_lds[40*128];  // 20480 B [c][p]; reused as redp/redf
  __shared__ float b2s[K], cys[K], cxs[K];  // 3072 B
  float* redp = xr_lds;             // [32][136] = 4352 floats
  float* redf = xr_lds + 4352;      // [128]

  int b   = blockIdx.x >> 7;          // 128 blocks per batch
  int n0  = (blockIdx.x & 127) << 7;  // 128 pixels per block
  int tid = threadIdx.x;
  int kgi = tid >> 4;                 // 0..31
  int k0  = kgi << 3;                 // 8 k per thread
  int p0  = (tid & 15) << 3;          // 8 px per thread

  if (tid < K) {
    b2s[tid] = b2[b*K + tid];
    cys[tid] = cspat[(b*K + tid)*2 + 0];
    cxs[tid] = cspat[(b*K + tid)*2 + 1];
  }

  float acc[64];   // [kk][pp] = acc[kk*8+pp]
  #pragma unroll
  for (int i = 0; i < 64; ++i) acc[i] = 0.f;

  const float* xb = x + (size_t)b*C*N;
  const float* ct = cst + (size_t)b*C*K;
  float4* cs4 = (float4*)cs_lds;
  float4* xr4 = (float4*)xr_lds;

  for (int t = 0; t < 5; ++t) {
    int cc0 = t * 40;
    __syncthreads();
    #pragma unroll
    for (int pass = 0; pass < 5; ++pass) {   // cs_t tile: linear copy 2560 f4
      int f = pass*512 + tid;
      cs4[f] = *(const float4*)&ct[(size_t)cc0*K + f*4];
    }
    #pragma unroll
    for (int pass = 0; pass < 3; ++pass) {   // x tile [40c][128p]: 1280 f4
      int idx = pass*512 + tid;
      if (idx < 1280) {
        int ci = idx >> 5, pq = idx & 31;
        xr4[idx] = *(const float4*)&xb[(size_t)(cc0 + ci)*N + n0 + pq*4];
      }
    }
    __syncthreads();
    #pragma unroll 2
    for (int c = 0; c < 40; ++c) {
      float4 cv0 = *(const float4*)&cs_lds[c*256 + k0];
      float4 cv1 = *(const float4*)&cs_lds[c*256 + k0 + 4];
      float4 xv0 = *(const float4*)&xr_lds[c*128 + p0];
      float4 xv1 = *(const float4*)&xr_lds[c*128 + p0 + 4];
      float cr[8] = {cv0.x, cv0.y, cv0.z, cv0.w, cv1.x, cv1.y, cv1.z, cv1.w};
      float xr[8] = {xv0.x, xv0.y, xv0.z, xv0.w, xv1.x, xv1.y, xv1.z, xv1.w};
      #pragma unroll
      for (int kk = 0; kk < 8; ++kk)
        #pragma unroll
        for (int pp = 0; pp < 8; ++pp)
          acc[kk*8 + pp] = fmaf(cr[kk], xr[pp], acc[kk*8 + pp]);
    }
  }
  __syncthreads();   // all x_lds reads done before redp overlay writes

  // ---- distances ----
  float py  = (float)(n0 >> 7);          // all 128 px share one image row
  float pxb = (float)(n0 & 127);
  float a2v[8], mn[8];
  #pragma unroll
  for (int pp = 0; pp < 8; ++pp) {
    a2v[pp] = a2[b*N + n0 + p0 + pp];
    mn[pp] = 1e30f;
  }
  #pragma unroll
  for (int kk = 0; kk < 8; ++kk) {
    int k = k0 + kk;
    float b2v = b2s[k], cy = cys[k], cx = cxs[k];
    float dy = py - cy, dyy = dy*dy;
    #pragma unroll
    for (int pp = 0; pp < 8; ++pp) {
      float dx = pxb + (float)(p0 + pp) - cx;
      float d = sqrtf(fmaxf(a2v[pp] + b2v - 2.f*acc[kk*8+pp], 1e-12f))
              + FACT*sqrtf(fmaxf(dyy + dx*dx, 1e-12f));
      acc[kk*8+pp] = d;
      mn[pp] = fminf(mn[pp], d);
    }
  }
  // ---- softmax over K: two-stage reduce across 32 kgroups ----
  #pragma unroll
  for (int pp = 0; pp < 8; ++pp) redp[kgi*136 + p0 + pp] = mn[pp];
  __syncthreads();
  if (tid < 128) {
    float m = redp[tid];
    #pragma unroll
    for (int g = 1; g < 32; ++g) m = fminf(m, redp[g*136 + tid]);
    redf[tid] = m;
  }
  __syncthreads();
  #pragma unroll
  for (int pp = 0; pp < 8; ++pp) mn[pp] = redf[p0 + pp];
  float sm[8] = {0.f,0.f,0.f,0.f,0.f,0.f,0.f,0.f};
  #pragma unroll
  for (int kk = 0; kk < 8; ++kk)
    #pragma unroll
    for (int pp = 0; pp < 8; ++pp) {
      float e = __expf(mn[pp] - acc[kk*8+pp]);
      acc[kk*8+pp] = e;
      sm[pp] += e;
    }
  __syncthreads();   // redf min-reads done before sum overwrite path
  #pragma unroll
  for (int pp = 0; pp < 8; ++pp) redp[kgi*136 + p0 + pp] = sm[pp];
  __syncthreads();
  if (tid < 128) {
    float s = redp[tid];
    #pragma unroll
    for (int g = 1; g < 32; ++g) s += redp[g*136 + tid];
    redf[tid] = 1.f / s;
  }
  __syncthreads();
  #pragma unroll
  for (int pp = 0; pp < 8; ++pp) {
    float inv = redf[p0 + pp];
    float* qp = Q + ((size_t)(b*N + n0 + p0 + pp))*K + k0;
    float4 v0 = make_float4(acc[0*8+pp]*inv, acc[1*8+pp]*inv,
                            acc[2*8+pp]*inv, acc[3*8+pp]*inv);
    float4 v1 = make_float4(acc[4*8+pp]*inv, acc[5*8+pp]*inv,
                            acc[6*8+pp]*inv, acc[7*8+pp]*inv);
    *(float4*)&qp[0] = v0;
    *(float4*)&qp[4] = v1;
  }
}

// ---------------------------------------------------------------------------
// update v7 stage 1: 512-thread blocks — same total Q staging as R16 (each
// 512-n Q slice staged by NCT=5 blocks) but 8 waves/block -> 16-24 waves/CU
// and per-thread staging halved. 512 thr = 64 kgroups(4k) x 8 cgroups(5c);
// block = 256k x 40c x 512n; grid = B*NCT*NT = 640. acc[20] (~52 VGPR, safe).
__global__ __launch_bounds__(512) void k_update3(
    const float* __restrict__ x, const float* __restrict__ Q,
    float* __restrict__ part) {
  __shared__ float q_lds[32*256];   // 32 KB [n][k]
  __shared__ float x_lds[40*34];    // 5.4 KB [c][n] pad 34
  int bid = blockIdx.x;             // B*NCT*NT = 640
  int b   = bid / (NCT*NT);
  int rem = bid - b*(NCT*NT);
  int ct  = rem >> 5;               // 0..4
  int nt  = rem & 31;               // 0..31
  int tid = threadIdx.x;
  int kg  = tid & 63;               // 64 kgroups
  int k0  = kg << 2;                // 4 k per thread
  int cg  = tid >> 6;               // 8 cgroups (wave-uniform)
  int cbase = cg * 5;               // 5 c per thread
  int c0  = ct * 40;

  float acc[20];                    // [kk][c] = acc[kk*5 + c]
  #pragma unroll
  for (int i = 0; i < 20; ++i) acc[i] = 0.f;

  const float* xb = x + (size_t)b*C*N + (size_t)c0*N;
  const float4* Q4 = (const float4*)(Q + (size_t)b*N*K);
  float4* q4 = (float4*)q_lds;

  for (int ch = 0; ch < 16; ++ch) {
    int nb = nt*512 + ch*32;
    __syncthreads();
    #pragma unroll
    for (int pass = 0; pass < 4; ++pass) {   // Q tile: 2048 f4 over 512 thr
      int idx = pass*512 + tid;
      q4[idx] = Q4[(size_t)(nb + (idx >> 6))*64 + (idx & 63)];
    }
    {                                        // x tile [40c][34n]: 1280 elems
      int idx = tid;
      #pragma unroll
      for (int pass = 0; pass < 3; ++pass) {
        if (idx < 1280) {
          int ci = idx >> 5, nn = idx & 31;
          x_lds[ci*34 + nn] = xb[(size_t)ci*N + nb + nn];
        }
        idx += 512;
      }
    }
    __syncthreads();
    #pragma unroll 4
    for (int nn = 0; nn < 32; nn += 2) {
      float4 qv0 = *(const float4*)&q_lds[nn*256 + k0];
      float4 qv1 = *(const float4*)&q_lds[(nn+1)*256 + k0];
      float qr0[4] = {qv0.x, qv0.y, qv0.z, qv0.w};
      float qr1[4] = {qv1.x, qv1.y, qv1.z, qv1.w};
      #pragma unroll
      for (int c = 0; c < 5; ++c) {
        float2 xv = *(const float2*)&x_lds[(cbase + c)*34 + nn]; // broadcast
        #pragma unroll
        for (int kk = 0; kk < 4; ++kk) {
          float a = acc[kk*5 + c];
          a = fmaf(qr0[kk], xv.x, a);
          a = fmaf(qr1[kk], xv.y, a);
          acc[kk*5 + c] = a;
        }
      }
    }
  }
  // coalesced f4 partial stores (consecutive kg -> consecutive 16B)
  float* pp = part + ((size_t)((b*NT + nt)*NCT + ct) * 40) * K;
  #pragma unroll
  for (int c = 0; c < 5; ++c) {
    float4 v = make_float4(acc[0*5+c], acc[1*5+c], acc[2*5+c], acc[3*5+c]);
    *(float4*)&pp[(size_t)(cbase + c)*K + k0] = v;
  }
}

// mass/spatial sums: mass[k] = sum_n Q[n][k], etc. grid = B*NTM, 128 n each.
__global__ __launch_bounds__(256) void k_mass(
    const float* __restrict__ Q, float* __restrict__ mpart) {
  int bid = blockIdx.x;             // B*NTM = 512
  int b = bid >> 7, nt = bid & 127;
  int tid = threadIdx.x;
  const float* Qb = Q + (size_t)b*N*K;
  int nbase = nt * 128;
  float mass = 0.f, sy = 0.f, sx = 0.f;
  for (int nn = 0; nn < 128; nn += 8) {
    float qv[8];
    #pragma unroll
    for (int j = 0; j < 8; ++j)
      qv[j] = Qb[(size_t)(nbase + nn + j)*K + tid];
    #pragma unroll
    for (int j = 0; j < 8; ++j) {
      int n = nbase + nn + j;
      mass += qv[j];
      sy += qv[j] * (float)(n >> 7);
      sx += qv[j] * (float)(n & 127);
    }
  }
  float* mp = mpart + (size_t)(b*NTM + nt) * 3 * K;
  mp[tid]       = mass;
  mp[K + tid]   = sy;
  mp[2*K + tid] = sx;
}

// stage 2: reduce NT partials per output element. grid = B*200.
__global__ __launch_bounds__(256) void k_reduce(
    const float* __restrict__ part, const float* __restrict__ mpart,
    float* __restrict__ sacc, float* __restrict__ macc,
    float* __restrict__ spacc) {
  int bid = blockIdx.x;        // B * 200
  int b = bid / 200;
  int r = bid % 200;
  int ct = r / 40, cw = r % 40;
  int tid = threadIdx.x;
  float s = 0.f;
  for (int nt = 0; nt < NT; ++nt)
    s += part[(((size_t)(b*NT + nt)*NCT + ct)*40 + cw)*K + tid];
  sacc[(size_t)(b*K + tid)*C + ct*40 + cw] = s;
  if (r == 0) {
    float m = 0.f, yy = 0.f, xx = 0.f;
    for (int nt = 0; nt < NTM; ++nt) {
      const float* mp = mpart + (size_t)(b*NTM + nt) * 3 * K;
      m  += mp[tid];
      yy += mp[K + tid];
      xx += mp[2*K + tid];
    }
    macc[b*K + tid] = m;
    spacc[(b*K + tid)*2 + 0] = yy;
    spacc[(b*K + tid)*2 + 1] = xx;
  }
}

// ---------------------------------------------------------------------------
// fallback update (atomic version, used only if ws too small for partials)
__global__ __launch_bounds__(256, 2) void k_update(
    const float* __restrict__ x, const float* __restrict__ Q,
    float* __restrict__ sacc, float* __restrict__ macc,
    float* __restrict__ spacc) {
  __shared__ float x_lds[32*28];
  int bid = blockIdx.x;
  int b = bid >> 9;
  int rest = bid & 511;
  int ct = rest >> 6;
  int nt = rest & 63;
  int tid = threadIdx.x;
  int c0 = ct * 25;

  float acc[25];
  #pragma unroll
  for (int c = 0; c < 25; ++c) acc[c] = 0.f;
  float mass = 0.f, sy = 0.f, sx = 0.f;

  const float* xb = x + (size_t)b*C*N + (size_t)c0*N;
  const float* Qb = Q + (size_t)b*N*K;

  for (int ch = 0; ch < 8; ++ch) {
    int nb = nt*256 + ch*32;
    __syncthreads();
    #pragma unroll
    for (int pass = 0; pass < 4; ++pass) {
      int idx = pass*256 + tid;
      if (idx < 800) {
        int ci = idx >> 5, nn = idx & 31;
        x_lds[nn*28 + ci] = xb[(size_t)ci*N + nb + nn];
      }
    }
    __syncthreads();
    float py  = (float)(nb >> 7);
    float pxb = (float)(nb & 127);
    #pragma unroll
    for (int n4 = 0; n4 < 8; ++n4) {
      float qv[4];
      #pragma unroll
      for (int j = 0; j < 4; ++j)
        qv[j] = Qb[(size_t)(nb + n4*4 + j)*K + tid];
      #pragma unroll
      for (int j = 0; j < 4; ++j) {
        int nn = n4*4 + j;
        float q = qv[j];
        if (ct == 0) {
          mass += q;
          sy += q * py;
          sx += q * (pxb + (float)nn);
        }
        const float* xr = &x_lds[nn*28];
        #pragma unroll
        for (int c4 = 0; c4 < 6; ++c4) {
          float4 xv = *(const float4*)&xr[c4*4];
          acc[c4*4+0] = fmaf(q, xv.x, acc[c4*4+0]);
          acc[c4*4+1] = fmaf(q, xv.y, acc[c4*4+1]);
          acc[c4*4+2] = fmaf(q, xv.z, acc[c4*4+2]);
          acc[c4*4+3] = fmaf(q, xv.w, acc[c4*4+3]);
        }
        acc[24] = fmaf(q, xr[24], acc[24]);
      }
    }
  }
  float* sp = sacc + ((size_t)(b*K + tid))*C + c0;
  #pragma unroll
  for (int c = 0; c < 25; ++c) atomicAdd(&sp[c], acc[c]);
  if (ct == 0) {
    atomicAdd(&macc[b*K + tid], mass);
    atomicAdd(&spacc[(b*K + tid)*2 + 0], sy);
    atomicAdd(&spacc[(b*K + tid)*2 + 1], sx);
  }
}

// finalize: divide by mass; write centers (row-major + transposed) and d_out
__global__ void k_final(const float* __restrict__ sacc, const float* __restrict__ macc,
                        const float* __restrict__ spacc, float* __restrict__ cs,
                        float* __restrict__ cst, float* __restrict__ cspat,
                        float* __restrict__ outc, int last) {
  int bk = blockIdx.x;
  int b = bk >> 8, kk = bk & 255;
  int c = threadIdx.x;
  float inv = 1.f / (macc[bk] + 1e-6f);
  if (c < C) {
    float v = sacc[(size_t)bk*C + c] * inv;
    cs[(size_t)bk*C + c] = v;
    cst[((size_t)(b*C + c))*K + kk] = v;
    if (last) outc[(size_t)bk*C + c] = v;
  } else if (c == C) {
    cspat[bk*2 + 0] = spacc[bk*2 + 0] * inv;
  } else if (c == C + 1) {
    cspat[bk*2 + 1] = spacc[bk*2 + 1] * inv;
  }
}

extern "C" void kernel_launch(void* const* d_in, const int* in_sizes, int n_in,
                              void* d_out, int out_size, void* d_ws, size_t ws_size,
                              hipStream_t stream) {
  const float* x = (const float*)d_in[0];
  float* out = (float*)d_out;
  float* ws  = (float*)d_ws;
  float* a2    = ws + OFF_A2;
  float* cs    = ws + OFF_CS;
  float* cspat = ws + OFF_CSPAT;
  float* b2    = ws + OFF_B2;
  float* sacc  = ws + OFF_SACC;
  float* macc  = ws + OFF_MACC;
  float* spacc = ws + OFF_SPACC;
  float* cst   = ws + OFF_CST;
  float* part  = ws + OFF_PART;
  float* mpart = ws + OFF_MPART;
  float* outc  = out + (size_t)B*N*K;
  int split = (ws_size >= WS_NEED) ? 1 : 0;

  hipLaunchKernelGGL(k_init, dim3(K), dim3(256), 0, stream, x, cs, cst, cspat);
  hipLaunchKernelGGL(k_a2, dim3(B*64), dim3(256), 0, stream, x, a2);
  for (int it = 0; it < ITERS; ++it) {
    hipLaunchKernelGGL(k_b2, dim3(B*K), dim3(64), 0, stream, cs, b2);
    hipLaunchKernelGGL(k_assign, dim3(B*128), dim3(512), 0, stream,
                       x, cst, cspat, b2, a2, out);
    if (split) {
      hipLaunchKernelGGL(k_update3, dim3(B*NCT*NT), dim3(512), 0, stream,
                         x, out, part);
      hipLaunchKernelGGL(k_mass, dim3(B*NTM), dim3(256), 0, stream,
                         out, mpart);
      hipLaunchKernelGGL(k_reduce, dim3(B*200), dim3(256), 0, stream,
                         part, mpart, sacc, macc, spacc);
    } else {
      hipMemsetAsync(sacc, 0, (size_t)(B*K*C + B*K + B*K*2)*sizeof(float), stream);
      hipLaunchKernelGGL(k_update, dim3(B*512), dim3(256), 0, stream,
                         x, out, sacc, macc, spacc);
    }
    hipLaunchKernelGGL(k_final, dim3(B*K), dim3(256), 0, stream,
                       sacc, macc, spacc, cs, cst, cspat, outc,
                       (it == ITERS-1) ? 1 : 0);
  }
}